// Round 6
// baseline (1123.778 us; speedup 1.0000x reference)
//
#include <hip/hip_runtime.h>

#define RD 256
#define BT 64
#define NTH 1024
#define T_STEPS 9

typedef __attribute__((ext_vector_type(8))) short short8;
typedef __attribute__((ext_vector_type(8))) _Float16 half8;
typedef __attribute__((ext_vector_type(4))) float f32x4;

// tanh(x) given z = 2x:  1 - 2/(exp(2x)+1).
__device__ __forceinline__ float tanh_from_2x(float z) {
  float e = __expf(z);
  float r = __builtin_amdgcn_rcpf(e + 1.0f);
  return __builtin_fmaf(-2.0f, r, 1.0f);
}
__device__ __forceinline__ f32x4 mfma16h(half8 a, half8 b, f32x4 c) {
  return __builtin_amdgcn_mfma_f32_16x16x32_f16(a, b, c, 0, 0, 0);
}
__device__ __forceinline__ unsigned pack2h(float a, float b) {
  unsigned short ua = __builtin_bit_cast(unsigned short, (_Float16)a);
  unsigned short ub = __builtin_bit_cast(unsigned short, (_Float16)b);
  return (unsigned)ua | ((unsigned)ub << 16);
}

// Pack B1/B2 into fp16 A-fragments, stream-ordered: chunk s = w*8+kk, then Mt.
// Lane l of tile (Mt,kk) holds A[r=Mt*16+(l&15)][k=kk*32+(l>>4)*8+i], i=0..7.
// Offset: ((s*16 + Mt)*512) + l*8  -> per-wave chunk stride is 8192 halves.
__global__ __launch_bounds__(64) void prep_w(const float* __restrict__ B1,
                                             const float* __restrict__ B2,
                                             _Float16* __restrict__ Wh) {
  const int blk = blockIdx.x;
  const int w = blk >> 7, rem = blk & 127;
  const int Mt = rem >> 3, kk = rem & 7;
  const int l = threadIdx.x, c = l & 15, g = l >> 4;
  const float* src = (w == 0 ? B1 : B2 + (size_t)(w - 1) * RD * RD)
                     + (size_t)(Mt * 16 + c) * RD + kk * 32 + g * 8;
  _Float16* d = Wh + (size_t)(((w * 8 + kk) * 16 + Mt) * 512) + l * 8;
  #pragma unroll
  for (int i = 0; i < 8; ++i) d[i] = (_Float16)src[i];
}

__global__ __launch_bounds__(NTH) void sde_main(
    const float* __restrict__ V, const float* __restrict__ inc,
    const float* __restrict__ W1, const float* __restrict__ b1,
    const float* __restrict__ W2, const float* __restrict__ b2,
    const float* __restrict__ rho1p, const float* __restrict__ rho2p,
    const float* __restrict__ rho3p, const float* __restrict__ rho4p,
    const float* __restrict__ lam1, const float* __restrict__ lam2,
    const float* __restrict__ Wro, const float* __restrict__ bro,
    const _Float16* __restrict__ Wh, float* __restrict__ out) {
  // Exchange buffer: R_t fp16 B-fragments; slot (kk,gq,b) at (kk*4+gq)*64+b,
  // element i holds R[k=kk*32+gq*8+i][b].
  __shared__ short8 Bex[2048];                  // 32 KB (aliases W2s)
  __shared__ float dW_s[T_STEPS * 8 * BT];      // 18 KB
  __shared__ float lam_e[9 * RD];               // 9 KB: 2*rB*lam (aliases actT)
  __shared__ float ro_part[16 * BT];            // 4 KB

  const int tid = threadIdx.x;
  const int wv = tid >> 6, l = tid & 63, c = l & 15, g = l >> 4;
  // wave wv owns row-tile Mt = wv (rows wv*16 .. wv*16+15), all 64 batches.
  const int b_base = blockIdx.x * BT;
  const float sa1 = 2.0f * rho1p[0], sa3 = 2.0f * rho3p[0];

  float* W2s  = (float*)Bex;   // 32 KB, prologue only
  float* actT = lam_e;         // 8 KB of 9 KB, prologue only

  // ---- phase A: stage W2, activations, dW ----
  {
    const float4* s = (const float4*)W2;
    float4* d = (float4*)W2s;
    d[tid] = s[tid];
    d[tid + 1024] = s[tid + 1024];
  }
  {
    const int b = tid & 63, h0 = (tid >> 6) << 1;
    const float* Vb = V + (size_t)(b_base + b) * 16;
    float v[16];
    #pragma unroll
    for (int k = 0; k < 16; ++k) v[k] = Vb[k];
    #pragma unroll
    for (int i = 0; i < 2; ++i) {
      const int h = h0 + i;
      float s = b1[h];
      #pragma unroll
      for (int k = 0; k < 16; ++k) s += v[k] * W1[h * 16 + k];
      actT[h * 64 + b] = tanh_from_2x(2.0f * s);
    }
  }
  if (tid < 512) {
    const int b = tid >> 3, m = tid & 7;
    const float* ib = inc + (size_t)(b_base + b) * 80 + m;
    dW_s[m * BT + b] = ib[0] + ib[8];
    #pragma unroll
    for (int t = 1; t < 9; ++t) dW_s[(t * 8 + m) * BT + b] = ib[(t + 1) * 8];
  }
  __syncthreads();

  // ---- phase B: R0 in C/D layout: rows wv*16+4g+i, cols nt*16+c ----
  float mast[4][4];
  #pragma unroll
  for (int i = 0; i < 4; ++i) {
    const float bb = b2[wv * 16 + 4 * g + i];
    #pragma unroll
    for (int nt = 0; nt < 4; ++nt) mast[nt][i] = bb;
  }
  #pragma unroll 4
  for (int h = 0; h < 32; ++h) {
    float a[4];
    #pragma unroll
    for (int nt = 0; nt < 4; ++nt) a[nt] = actT[h * 64 + nt * 16 + c];
    #pragma unroll
    for (int i = 0; i < 4; ++i) {
      const float w2v = W2s[(wv * 16 + 4 * g + i) * 32 + h];
      #pragma unroll
      for (int nt = 0; nt < 4; ++nt) mast[nt][i] += w2v * a[nt];
    }
  }

  auto partials = [&](int t) {
    float s[4] = {0.f, 0.f, 0.f, 0.f};
    #pragma unroll
    for (int i = 0; i < 4; ++i) {
      const float wr = Wro[t * RD + wv * 16 + 4 * g + i];
      #pragma unroll
      for (int nt = 0; nt < 4; ++nt) s[nt] += wr * mast[nt][i];
    }
    #pragma unroll
    for (int nt = 0; nt < 4; ++nt) {
      s[nt] += __shfl_xor(s[nt], 16);
      s[nt] += __shfl_xor(s[nt], 32);
    }
    if (g == 0) {
      #pragma unroll
      for (int nt = 0; nt < 4; ++nt) ro_part[wv * 64 + nt * 16 + c] = s[nt];
    }
  };

  // master fp32 -> fp16 exchange fragments.  Row wv*16+4g+i lives at
  // kk=wv>>1, gq=2*(wv&1)+(g>>1), element 4*(g&1)+i.
  auto write_ex = [&]() {
    const int kk_w = wv >> 1;
    const int gq = 2 * (wv & 1) + (g >> 1);
    const int hb = g & 1;
    #pragma unroll
    for (int nt = 0; nt < 4; ++nt) {
      const int slot = (kk_w * 4 + gq) * 64 + nt * 16 + c;
      uint2 pk;
      pk.x = pack2h(mast[nt][0], mast[nt][1]);
      pk.y = pack2h(mast[nt][2], mast[nt][3]);
      *((uint2*)((char*)&Bex[slot] + hb * 8)) = pk;
    }
  };

  partials(0);
  __syncthreads();   // W2s/actT reads done; ro_part(0) visible
  {
    const float rb2 = 2.0f * rho2p[0], rb4 = 2.0f * rho4p[0];
    for (int j = tid; j < 2304; j += NTH)
      lam_e[j] = (j < 256) ? rb2 * lam1[j] : rb4 * lam2[j - 256];
  }
  if (tid < BT) {
    float x = bro[0];
    #pragma unroll
    for (int q = 0; q < 16; ++q) x += ro_part[q * 64 + tid];
    out[(size_t)(b_base + tid) * 10] = x;
  }
  write_ex();
  __syncthreads();   // lam_e + exchange(R0) visible

  const _Float16* pA0 = Wh + wv * 512 + l * 8;  // wave's tile in chunk 0

  for (int t = 0; t < T_STEPS; ++t) {
    // B-fragments for the whole t-step (all 9 w reuse them)
    half8 Breg[8][4];
    #pragma unroll
    for (int kk = 0; kk < 8; ++kk)
      #pragma unroll
      for (int nt = 0; nt < 4; ++nt)
        Breg[kk][nt] = __builtin_bit_cast(
            half8, Bex[(kk * 4 + g) * 64 + nt * 16 + c]);

    // rolling 4-deep A prefetch over the 72-chunk stream (stride 8192)
    half8 Ab[4];
    Ab[0] = *(const half8*)(pA0);
    Ab[1] = *(const half8*)(pA0 + 8192);
    Ab[2] = *(const half8*)(pA0 + 2 * 8192);
    Ab[3] = *(const half8*)(pA0 + 3 * 8192);
    const _Float16* pPre = pA0 + 4 * 8192;

    #pragma unroll 1
    for (int w = 0; w < 9; ++w) {
      f32x4 acc[4];
      const f32x4 zero = {0.f, 0.f, 0.f, 0.f};
      acc[0] = zero; acc[1] = zero; acc[2] = zero; acc[3] = zero;

      #pragma unroll
      for (int kk = 0; kk < 8; ++kk) {
        const int cur = kk & 3;  // (w*8+kk)&3 == kk&3
        #pragma unroll
        for (int nt = 0; nt < 4; ++nt)
          acc[nt] = mfma16h(Ab[cur], Breg[kk][nt], acc[nt]);
        if (w * 8 + kk + 4 < 72) {
          Ab[cur] = *(const half8*)(pPre);
          pPre += 8192;
        }
      }

      const float sA = (w == 0) ? sa1 : sa3;
      float coef[4];
      if (w == 0) {
        coef[0] = 1.0f; coef[1] = 1.0f; coef[2] = 1.0f; coef[3] = 1.0f;
      } else {
        #pragma unroll
        for (int nt = 0; nt < 4; ++nt)
          coef[nt] = dW_s[((t * 8) + (w - 1)) * BT + nt * 16 + c];
      }
      #pragma unroll
      for (int i = 0; i < 4; ++i) {
        const float le = lam_e[w * RD + wv * 16 + 4 * g + i];
        #pragma unroll
        for (int nt = 0; nt < 4; ++nt) {
          const float th = tanh_from_2x(__builtin_fmaf(sA, acc[nt][i], le));
          mast[nt][i] = __builtin_fmaf(coef[nt], th, mast[nt][i]);
        }
      }
    }

    partials(t + 1);
    __syncthreads();            // Bex reads (Breg) + ro_part writes complete
    if (tid < BT) {
      float x = bro[t + 1];
      #pragma unroll
      for (int q = 0; q < 16; ++q) x += ro_part[q * 64 + tid];
      out[(size_t)(b_base + tid) * 10 + (t + 1)] = x;
    }
    if (t < T_STEPS - 1) write_ex();
    __syncthreads();            // exchange(R_{t+1}) visible
  }
}

extern "C" void kernel_launch(void* const* d_in, const int* in_sizes, int n_in,
                              void* d_out, int out_size, void* d_ws, size_t ws_size,
                              hipStream_t stream) {
  const float* V    = (const float*)d_in[0];
  const float* inc  = (const float*)d_in[1];
  const float* W1   = (const float*)d_in[2];
  const float* b1   = (const float*)d_in[3];
  const float* W2   = (const float*)d_in[4];
  const float* b2   = (const float*)d_in[5];
  const float* rho1 = (const float*)d_in[6];
  const float* rho2 = (const float*)d_in[7];
  const float* rho3 = (const float*)d_in[8];
  const float* rho4 = (const float*)d_in[9];
  const float* B1   = (const float*)d_in[10];
  const float* B2   = (const float*)d_in[11];
  const float* lam1 = (const float*)d_in[12];
  const float* lam2 = (const float*)d_in[13];
  const float* Wro  = (const float*)d_in[14];
  const float* bro  = (const float*)d_in[15];
  float* out = (float*)d_out;

  _Float16* Wh = (_Float16*)d_ws;   // 9*16*8*512 halves = 1.18 MB

  const int B = in_sizes[0] / 16;

  prep_w<<<9 * 16 * 8, 64, 0, stream>>>(B1, B2, Wh);
  sde_main<<<B / BT, NTH, 0, stream>>>(V, inc, W1, b1, W2, b2,
                                       rho1, rho2, rho3, rho4,
                                       lam1, lam2, Wro, bro, Wh, out);
}

// Round 7
// 294.449 us; speedup vs baseline: 3.8165x; 3.8165x over previous
//
#include <hip/hip_runtime.h>

#define RD 256
#define BT 64
#define NTH 512
#define T_STEPS 9

typedef __attribute__((ext_vector_type(8))) short short8;
typedef __attribute__((ext_vector_type(8))) _Float16 half8;
typedef __attribute__((ext_vector_type(4))) float f32x4;

// tanh(x) given z = 2x:  1 - 2/(exp(2x)+1).
__device__ __forceinline__ float tanh_from_2x(float z) {
  float e = __expf(z);
  float r = __builtin_amdgcn_rcpf(e + 1.0f);
  return __builtin_fmaf(-2.0f, r, 1.0f);
}
__device__ __forceinline__ f32x4 mfma16h(half8 a, half8 b, f32x4 c) {
  return __builtin_amdgcn_mfma_f32_16x16x32_f16(a, b, c, 0, 0, 0);
}
__device__ __forceinline__ unsigned pack2h(float a, float b) {
  unsigned short ua = __builtin_bit_cast(unsigned short, (_Float16)a);
  unsigned short ub = __builtin_bit_cast(unsigned short, (_Float16)b);
  return (unsigned)ua | ((unsigned)ub << 16);
}

// Pack B1/B2 into fp16 A-fragments, stream-ordered: chunk s = w*8+kk, then Mt.
// Lane l of tile (Mt,kk) holds A[r=Mt*16+(l&15)][k=kk*32+(l>>4)*8+i], i=0..7.
// Offset: ((s*16 + Mt)*512) + l*8  -> chunk stride is 8192 halves (16 KB).
__global__ __launch_bounds__(64) void prep_w(const float* __restrict__ B1,
                                             const float* __restrict__ B2,
                                             _Float16* __restrict__ Wh) {
  const int blk = blockIdx.x;
  const int w = blk >> 7, rem = blk & 127;
  const int Mt = rem >> 3, kk = rem & 7;
  const int l = threadIdx.x, c = l & 15, g = l >> 4;
  const float* src = (w == 0 ? B1 : B2 + (size_t)(w - 1) * RD * RD)
                     + (size_t)(Mt * 16 + c) * RD + kk * 32 + g * 8;
  _Float16* d = Wh + (size_t)(((w * 8 + kk) * 16 + Mt) * 512) + l * 8;
  #pragma unroll
  for (int i = 0; i < 8; ++i) d[i] = (_Float16)src[i];
}

__global__ __launch_bounds__(NTH, 2) void sde_main(
    const float* __restrict__ V, const float* __restrict__ inc,
    const float* __restrict__ W1, const float* __restrict__ b1,
    const float* __restrict__ W2, const float* __restrict__ b2,
    const float* __restrict__ rho1p, const float* __restrict__ rho2p,
    const float* __restrict__ rho3p, const float* __restrict__ rho4p,
    const float* __restrict__ lam1, const float* __restrict__ lam2,
    const float* __restrict__ Wro, const float* __restrict__ bro,
    const _Float16* __restrict__ Wh, float* __restrict__ out) {
  // Exchange buffer: R_t fp16 B-fragments; slot (kk,gq,b) at (kk*4+gq)*64+b,
  // element i holds R[k=kk*32+gq*8+i][b].
  __shared__ short8 Bex[2048];                  // 32 KB (aliases W2s)
  __shared__ float dW_s[T_STEPS * 8 * BT];      // 18 KB
  __shared__ float lam_e[9 * RD];               // 9 KB: 2*rB*lam (aliases actT)
  __shared__ float ro_part[8 * BT];             // 2 KB

  const int tid = threadIdx.x;
  const int wv = tid >> 6, l = tid & 63, c = l & 15, g = l >> 4;
  // wave wv in [0,8): owns rows [32*wv, 32*wv+32) (Mt = 2wv, 2wv+1), all 64 b.
  const int b_base = blockIdx.x * BT;
  const float sa1 = 2.0f * rho1p[0], sa3 = 2.0f * rho3p[0];

  float* W2s  = (float*)Bex;   // 32 KB, prologue only
  float* actT = lam_e;         // 8 KB of 9 KB, prologue only

  // ---- phase A: stage W2, activations, dW ----
  {
    const float4* s = (const float4*)W2;
    float4* d = (float4*)W2s;
    #pragma unroll
    for (int j = 0; j < 4; ++j) d[j * NTH + tid] = s[j * NTH + tid];
  }
  {
    const int b = tid & 63, h0 = (tid >> 6) << 2;
    const float* Vb = V + (size_t)(b_base + b) * 16;
    float v[16];
    #pragma unroll
    for (int k = 0; k < 16; ++k) v[k] = Vb[k];
    #pragma unroll
    for (int i = 0; i < 4; ++i) {
      const int h = h0 + i;
      float s = b1[h];
      #pragma unroll
      for (int k = 0; k < 16; ++k) s += v[k] * W1[h * 16 + k];
      actT[h * 64 + b] = tanh_from_2x(2.0f * s);
    }
  }
  {
    const int b = tid >> 3, m = tid & 7;
    const float* ib = inc + (size_t)(b_base + b) * 80 + m;
    dW_s[m * BT + b] = ib[0] + ib[8];
    #pragma unroll
    for (int t = 1; t < 9; ++t) dW_s[(t * 8 + m) * BT + b] = ib[(t + 1) * 8];
  }
  __syncthreads();

  // ---- phase B: R0 in C/D layout: rows 32wv+16mt+4g+i, cols nt*16+c ----
  float mast[2][4][4];
  #pragma unroll
  for (int mt = 0; mt < 2; ++mt)
    #pragma unroll
    for (int i = 0; i < 4; ++i) {
      const float bb = b2[32 * wv + 16 * mt + 4 * g + i];
      #pragma unroll
      for (int nt = 0; nt < 4; ++nt) mast[mt][nt][i] = bb;
    }
  #pragma unroll 4
  for (int h = 0; h < 32; ++h) {
    float a[4];
    #pragma unroll
    for (int nt = 0; nt < 4; ++nt) a[nt] = actT[h * 64 + nt * 16 + c];
    #pragma unroll
    for (int mt = 0; mt < 2; ++mt)
      #pragma unroll
      for (int i = 0; i < 4; ++i) {
        const float w2v = W2s[(32 * wv + 16 * mt + 4 * g + i) * 32 + h];
        #pragma unroll
        for (int nt = 0; nt < 4; ++nt) mast[mt][nt][i] += w2v * a[nt];
      }
  }

  auto partials = [&](int t) {
    float s[4] = {0.f, 0.f, 0.f, 0.f};
    #pragma unroll
    for (int mt = 0; mt < 2; ++mt)
      #pragma unroll
      for (int i = 0; i < 4; ++i) {
        const float wr = Wro[t * RD + 32 * wv + 16 * mt + 4 * g + i];
        #pragma unroll
        for (int nt = 0; nt < 4; ++nt) s[nt] += wr * mast[mt][nt][i];
      }
    #pragma unroll
    for (int nt = 0; nt < 4; ++nt) {
      s[nt] += __shfl_xor(s[nt], 16);
      s[nt] += __shfl_xor(s[nt], 32);
    }
    if (g == 0) {
      #pragma unroll
      for (int nt = 0; nt < 4; ++nt) ro_part[wv * BT + nt * 16 + c] = s[nt];
    }
  };

  // master fp32 -> fp16 exchange fragments.  Row 32wv+16mt+4g+i is k-chunk
  // kk=wv, gq = 2mt+(g>>1), in-slot element 4*(g&1)+i.
  auto write_ex = [&]() {
    #pragma unroll
    for (int mt = 0; mt < 2; ++mt) {
      const int gq = 2 * mt + (g >> 1);
      const int hb = g & 1;
      #pragma unroll
      for (int nt = 0; nt < 4; ++nt) {
        const int slot = (wv * 4 + gq) * 64 + nt * 16 + c;
        uint2 pk;
        pk.x = pack2h(mast[mt][nt][0], mast[mt][nt][1]);
        pk.y = pack2h(mast[mt][nt][2], mast[mt][nt][3]);
        *((uint2*)((char*)&Bex[slot] + hb * 8)) = pk;
      }
    }
  };

  partials(0);
  __syncthreads();   // W2s/actT reads done; ro_part(0) visible
  {
    const float rb2 = 2.0f * rho2p[0], rb4 = 2.0f * rho4p[0];
    for (int j = tid; j < 2304; j += NTH)
      lam_e[j] = (j < 256) ? rb2 * lam1[j] : rb4 * lam2[j - 256];
  }
  if (tid < BT) {
    float x = bro[0];
    #pragma unroll
    for (int q = 0; q < 8; ++q) x += ro_part[q * BT + tid];
    out[(size_t)(b_base + tid) * 10] = x;
  }
  write_ex();
  __syncthreads();   // lam_e + exchange(R0) visible

  const _Float16* pA0 = Wh + 2 * wv * 512 + l * 8;  // wave's Mt pair in chunk 0

  for (int t = 0; t < T_STEPS; ++t) {
    // B-fragments for the whole t-step (all 9 w reuse them)
    half8 Breg[8][4];
    #pragma unroll
    for (int kk = 0; kk < 8; ++kk)
      #pragma unroll
      for (int nt = 0; nt < 4; ++nt)
        Breg[kk][nt] = __builtin_bit_cast(
            half8, Bex[(kk * 4 + g) * 64 + nt * 16 + c]);

    // rolling 2-deep A prefetch over the 72-chunk stream (stride 8192)
    half8 Ab[2][2];
    Ab[0][0] = *(const half8*)(pA0);
    Ab[0][1] = *(const half8*)(pA0 + 512);
    Ab[1][0] = *(const half8*)(pA0 + 8192);
    Ab[1][1] = *(const half8*)(pA0 + 8192 + 512);
    const _Float16* pPre = pA0 + 2 * 8192;

    #pragma unroll 1
    for (int w = 0; w < 9; ++w) {
      f32x4 acc[2][4];
      const f32x4 zero = {0.f, 0.f, 0.f, 0.f};
      #pragma unroll
      for (int mt = 0; mt < 2; ++mt)
        #pragma unroll
        for (int nt = 0; nt < 4; ++nt) acc[mt][nt] = zero;

      #pragma unroll
      for (int kk = 0; kk < 8; ++kk) {
        const int cur = kk & 1;  // (w*8+kk)&1 == kk&1
        #pragma unroll
        for (int mt = 0; mt < 2; ++mt)
          #pragma unroll
          for (int nt = 0; nt < 4; ++nt)
            acc[mt][nt] = mfma16h(Ab[cur][mt], Breg[kk][nt], acc[mt][nt]);
        if (w * 8 + kk + 2 < 72) {
          Ab[cur][0] = *(const half8*)(pPre);
          Ab[cur][1] = *(const half8*)(pPre + 512);
          pPre += 8192;
        }
      }

      const float sA = (w == 0) ? sa1 : sa3;
      float coef[4];
      if (w == 0) {
        coef[0] = 1.0f; coef[1] = 1.0f; coef[2] = 1.0f; coef[3] = 1.0f;
      } else {
        #pragma unroll
        for (int nt = 0; nt < 4; ++nt)
          coef[nt] = dW_s[((t * 8) + (w - 1)) * BT + nt * 16 + c];
      }
      #pragma unroll
      for (int mt = 0; mt < 2; ++mt)
        #pragma unroll
        for (int i = 0; i < 4; ++i) {
          const float le = lam_e[w * RD + 32 * wv + 16 * mt + 4 * g + i];
          #pragma unroll
          for (int nt = 0; nt < 4; ++nt) {
            const float th = tanh_from_2x(__builtin_fmaf(sA, acc[mt][nt][i], le));
            mast[mt][nt][i] = __builtin_fmaf(coef[nt], th, mast[mt][nt][i]);
          }
        }
    }

    partials(t + 1);
    __syncthreads();            // Bex reads (Breg) + ro_part writes complete
    if (tid < BT) {
      float x = bro[t + 1];
      #pragma unroll
      for (int q = 0; q < 8; ++q) x += ro_part[q * BT + tid];
      out[(size_t)(b_base + tid) * 10 + (t + 1)] = x;
    }
    if (t < T_STEPS - 1) write_ex();
    __syncthreads();            // exchange(R_{t+1}) visible
  }
}

extern "C" void kernel_launch(void* const* d_in, const int* in_sizes, int n_in,
                              void* d_out, int out_size, void* d_ws, size_t ws_size,
                              hipStream_t stream) {
  const float* V    = (const float*)d_in[0];
  const float* inc  = (const float*)d_in[1];
  const float* W1   = (const float*)d_in[2];
  const float* b1   = (const float*)d_in[3];
  const float* W2   = (const float*)d_in[4];
  const float* b2   = (const float*)d_in[5];
  const float* rho1 = (const float*)d_in[6];
  const float* rho2 = (const float*)d_in[7];
  const float* rho3 = (const float*)d_in[8];
  const float* rho4 = (const float*)d_in[9];
  const float* B1   = (const float*)d_in[10];
  const float* B2   = (const float*)d_in[11];
  const float* lam1 = (const float*)d_in[12];
  const float* lam2 = (const float*)d_in[13];
  const float* Wro  = (const float*)d_in[14];
  const float* bro  = (const float*)d_in[15];
  float* out = (float*)d_out;

  _Float16* Wh = (_Float16*)d_ws;   // 9*16*8*512 halves = 1.18 MB

  const int B = in_sizes[0] / 16;

  prep_w<<<9 * 16 * 8, 64, 0, stream>>>(B1, B2, Wh);
  sde_main<<<B / BT, NTH, 0, stream>>>(V, inc, W1, b1, W2, b2,
                                       rho1, rho2, rho3, rho4,
                                       lam1, lam2, Wro, bro, Wh, out);
}